// Round 16
// baseline (83.239 us; speedup 1.0000x reference)
//
#include <hip/hip_runtime.h>
#include <math.h>

typedef _Float16 f16;
typedef f16   f16x4 __attribute__((ext_vector_type(4)));
typedef f16   f16x8 __attribute__((ext_vector_type(8)));
typedef float f32x4 __attribute__((ext_vector_type(4)));

#define B_ROWS 16384
#define PC 16
#define EPS_SIM 1e-4f
#define LOG_MIN_F (-18.420680743952367f)
#define KL_IDX  (B_ROWS + B_ROWS * 512)   // 8404992
#define OR_IDX  (KL_IDX + 1)

// direct global->LDS async copy, 16B per lane (lds dest = uniform base + lane*16)
#define GLD16(gp, lp) __builtin_amdgcn_global_load_lds( \
    (const __attribute__((address_space(1))) void*)(gp), \
    (__attribute__((address_space(3))) void*)(lp), 16, 0, 0)

// ---------------------------------------------------------------------------
// prep: ortho partials (blocks 0-7) + weight/proto f32->f16 + pnorm + init.
// x is NOT converted here (G1 converts in-kernel).  810 blocks.
// ---------------------------------------------------------------------------
__device__ __forceinline__ void conv4(const float* __restrict__ src,
                                      f16* __restrict__ dst, int i)
{
    float4 v = ((const float4*)src)[i];
    f16x4 o = { (f16)v.x, (f16)v.y, (f16)v.z, (f16)v.w };
    ((f16x4*)dst)[i] = o;
}

__global__ __launch_bounds__(256)
void prep_kernel(const float* __restrict__ W1,  const float* __restrict__ W2,
                 const float* __restrict__ Wd1, const float* __restrict__ Wd2,
                 const float* __restrict__ protos,
                 f16* __restrict__ W1h,  f16* __restrict__ W2h,
                 f16* __restrict__ Wd1h, f16* __restrict__ Wd2h,
                 f16* __restrict__ ph,
                 float* __restrict__ pnorm, float* __restrict__ opart,
                 float* __restrict__ S, float* __restrict__ Mn,
                 float* __restrict__ out)
{
    __shared__ float pk[PC][257];
    __shared__ float red[256];
    int blk = blockIdx.x, t = threadIdx.x;

    if (blk < 8) {                      // ortho: one class per block, parallel
        int c = blk;
        for (int i = t; i < PC * 256; i += 256)
            pk[i >> 8][i & 255] = protos[c * PC * 256 + i];
        __syncthreads();
        float mean = 0.f;
#pragma unroll
        for (int i = 0; i < PC; ++i) mean += pk[i][t];
        mean *= (1.f / (float)PC);
#pragma unroll
        for (int i = 0; i < PC; ++i) pk[i][t] -= mean;
        __syncthreads();
        int i = t >> 4, j = t & 15;
        float gg = 0.f;
#pragma unroll 8
        for (int l = 0; l < 256; ++l) gg = fmaf(pk[i][l], pk[j][l], gg);
        gg -= (i == j) ? 1.f : 0.f;
        red[t] = gg * gg;
        __syncthreads();
        for (int s = 128; s; s >>= 1) { if (t < s) red[t] += red[t + s]; __syncthreads(); }
        if (t == 0) opart[c] = sqrtf(red[0]);     // plain store, summed later
        return;
    }
    int b2 = blk - 8;
    if (b2 < 256)          conv4(W1,  W1h,  b2 * 256 + t);
    else if (b2 < 512)     conv4(W2,  W2h,  (b2 - 256) * 256 + t);
    else if (b2 < 576)     conv4(Wd1, Wd1h, (b2 - 512) * 256 + t);
    else if (b2 < 704)     conv4(Wd2, Wd2h, (b2 - 576) * 256 + t);
    else if (b2 < 736)     conv4(protos, ph, (b2 - 704) * 256 + t);
    else if (b2 < 738) {
        // pnorm from f16-ROUNDED protos (consistent with MFMA cross term)
        int tt = (b2 - 736) * 256 + t;             // [0,512)
        int row = tt >> 2, q = tt & 3;
        const float* pr = protos + (size_t)row * 256 + q * 64;
        float s = 0.f;
#pragma unroll
        for (int j = 0; j < 16; ++j) {
            float4 v = *(const float4*)(pr + j * 4);
            float r0 = (float)(f16)v.x, r1 = (float)(f16)v.y;
            float r2 = (float)(f16)v.z, r3 = (float)(f16)v.w;
            s = fmaf(r0, r0, s); s = fmaf(r1, r1, s);
            s = fmaf(r2, r2, s); s = fmaf(r3, r3, s);
        }
        s += __shfl_xor(s, 1, 64);
        s += __shfl_xor(s, 2, 64);
        if (q == 0) pnorm[row] = s;
    } else {
        int i = (b2 - 738) * 256 + t;              // [0,16384)
        S[i] = 0.f; Mn[i] = 0.f;
        if (i == 0) out[KL_IDX] = 0.f;
    }
}

// ---------------------------------------------------------------------------
// Pure-f16 MFMA GEMM, BM=128 x BN=128, BK=32, 4 waves (2x2, 64x64 each),
// 16KB single-buffer LDS, two-barrier loop (round-14-proven):
//   barrier -> ds_read frags -> barrier -> stage(tk+1) -> MFMA [-> CONV write]
// CONV=1: A read directly as f32 (reg-staged loads issued before MFMA,
//         f16 convert + swizzled ds_write after MFMA; top barrier syncs lgkm).
// MODE 0: relu -> f16 store
// MODE 3: tanh -> f32 store
// MODE 4: y<2 mu f16 store + |mu_h|^2 row-reduce; y>=2 logVar -> S row-reduce
// MODE 5: y<2 relu f16 store (dh); y==2 raw f16 cross -> Xc
// ---------------------------------------------------------------------------
template<int MODE, int KK, int CONV>
__global__ __launch_bounds__(256, 2)
void gemm_mfma(const float* __restrict__ A32, const f16* __restrict__ A,
               const f16* __restrict__ B, const f16* __restrict__ P,
               const float* __restrict__ bias,
               f16* __restrict__ C16, float* __restrict__ Cf,
               float* __restrict__ Srow, float* __restrict__ Mnorm,
               f16* __restrict__ Xc, int ldc)
{
    __shared__ __align__(16) f16 LA[128][32];
    __shared__ __align__(16) f16 LB[128][32];

    const int t = threadIdx.x, lane = t & 63, wave = t >> 6;
    const int wm = wave >> 1, wn = wave & 1;
    const int bm = blockIdx.x * 128;
    const int y  = blockIdx.y;
    const bool proto = (MODE == 5) && (y == 2);
    const int bn  = y * 128;                      // output col base (non-proto)
    const int bnB = proto ? 0 : bn;               // B row base
    const f16* Bp = proto ? P : B;
    const int rA = lane & 15, g = lane >> 4;
    const int srow = lane >> 2, cp = lane & 3;    // staging: 16 rows x 4 chunks

    f32x4 acc[4][4];
    const f32x4 z4 = {0.f, 0.f, 0.f, 0.f};
#pragma unroll
    for (int i = 0; i < 4; ++i)
#pragma unroll
        for (int j = 0; j < 4; ++j) acc[i][j] = z4;

    // A-conversion map (CONV): lane -> 4 rows x (4 f32 -> 4 f16)
    const int cr8 = lane >> 3, ch = lane & 7;

    auto stageB = [&](int kt) {          // 2 GLD16 per thread (B half)
#pragma unroll
        for (int s = 0; s < 2; ++s) {
            int row = wave * 32 + s * 16 + srow;
            int lc  = (cp - (row >> 1)) & 3;      // inverse swizzle on SOURCE
            GLD16(Bp + (size_t)(bnB + row) * KK + kt * 32 + lc * 8,
                  &LB[wave * 32 + s * 16][0]);
        }
    };
    auto stageA = [&](int kt) {          // 2 GLD16 per thread (A half, !CONV)
#pragma unroll
        for (int s = 0; s < 2; ++s) {
            int row = wave * 32 + s * 16 + srow;
            int lc  = (cp - (row >> 1)) & 3;
            GLD16(A + (size_t)(bm + row) * KK + kt * 32 + lc * 8,
                  &LA[wave * 32 + s * 16][0]);
        }
    };
    auto writeA = [&](const float4* rr) {  // CONV: swizzled f16 ds_write
#pragma unroll
        for (int s = 0; s < 4; ++s) {
            int r8 = wave * 32 + s * 8 + cr8;
            f16x4 o = {(f16)rr[s].x, (f16)rr[s].y, (f16)rr[s].z, (f16)rr[s].w};
            *(f16x4*)((char*)&LA[r8][0] +
                      ((((ch >> 1) + (r8 >> 1)) & 3) * 16 + (ch & 1) * 8)) = o;
        }
    };

    constexpr int T = KK / 32;
    // prologue: stage tile 0
    stageB(0);
    if (CONV) {
        float4 rr[4];
#pragma unroll
        for (int s = 0; s < 4; ++s) {
            int r8 = wave * 32 + s * 8 + cr8;
            rr[s] = *(const float4*)(A32 + (size_t)(bm + r8) * KK + ch * 4);
        }
        writeA(rr);
    } else {
        stageA(0);
    }

    for (int tk = 0; tk < T; ++tk) {
        __syncthreads();                 // vmcnt+lgkm drained: tile tk in LDS

        f16x8 a[4], b[4];
#pragma unroll
        for (int i = 0; i < 4; ++i) {
            int m = wm * 64 + i * 16 + rA;
            int c = ((g + (m >> 1)) & 3) * 8;     // swizzled READ
            a[i] = *(const f16x8*)&LA[m][c];
            int n = wn * 64 + i * 16 + rA;
            int cn = ((g + (n >> 1)) & 3) * 8;
            b[i] = *(const f16x8*)&LB[n][cn];
        }

        __syncthreads();                 // all reads done; safe to overwrite

        float4 rr[4];
        if (tk + 1 < T) {
            stageB(tk + 1);              // async B loads fly under the MFMAs
            if (CONV) {                  // issue-early: f32 A loads
#pragma unroll
                for (int s = 0; s < 4; ++s) {
                    int r8 = wave * 32 + s * 8 + cr8;
                    rr[s] = *(const float4*)(A32 + (size_t)(bm + r8) * KK +
                                             (tk + 1) * 32 + ch * 4);
                }
            } else {
                stageA(tk + 1);
            }
        }

#pragma unroll
        for (int i = 0; i < 4; ++i)
#pragma unroll
            for (int j = 0; j < 4; ++j)
                acc[i][j] = __builtin_amdgcn_mfma_f32_16x16x32_f16(a[i], b[j], acc[i][j], 0, 0, 0);

        if (CONV && tk + 1 < T)          // write-late: load latency hidden
            writeA(rr);
    }

    if (proto) {
        // raw cross-products -> Xc[16384][128] as f16 (no bias, no reduce)
#pragma unroll
        for (int i = 0; i < 4; ++i)
#pragma unroll
            for (int r = 0; r < 4; ++r) {
                size_t row = bm + wm * 64 + i * 16 + g * 4 + r;
#pragma unroll
                for (int j = 0; j < 4; ++j) {
                    int col = wn * 64 + j * 16 + rA;
                    Xc[row * 128 + col] = (f16)acc[i][j][r];
                }
            }
        return;
    }

    float bv[4];
#pragma unroll
    for (int j = 0; j < 4; ++j) bv[j] = bias[bn + wn * 64 + j * 16 + rA];

    if (MODE == 4 && y >= 2) {
        // logVar columns: S[row] += partial mean(0.5 e^lv - 0.5 lv - 0.5)
#pragma unroll
        for (int i = 0; i < 4; ++i)
#pragma unroll
            for (int r = 0; r < 4; ++r) {
                int row = bm + wm * 64 + i * 16 + g * 4 + r;
                float s = 0.f;
#pragma unroll
                for (int j = 0; j < 4; ++j) {
                    float lv = acc[i][j][r] + bv[j];
                    lv = fminf(fmaxf(lv, LOG_MIN_F), -LOG_MIN_F);
                    s += 0.5f * __expf(lv) - 0.5f * lv - 0.5f;
                }
                s += __shfl_xor(s, 1, 64); s += __shfl_xor(s, 2, 64);
                s += __shfl_xor(s, 4, 64); s += __shfl_xor(s, 8, 64);
                if (rA == 0) atomicAdd(&Srow[row], s * (1.f / 256.f));
            }
        return;
    }

#pragma unroll
    for (int i = 0; i < 4; ++i)
#pragma unroll
        for (int r = 0; r < 4; ++r) {
            size_t row = bm + wm * 64 + i * 16 + g * 4 + r;
            float sq = 0.f;
#pragma unroll
            for (int j = 0; j < 4; ++j) {
                int col = bn + wn * 64 + j * 16 + rA;
                float v = acc[i][j][r] + bv[j];
                if (MODE == 0 || MODE == 5) v = fmaxf(v, 0.f);
                if (MODE == 3) {
                    float e = __expf(2.f * v);
                    Cf[row * ldc + col] = 1.f - 2.f / (e + 1.f);
                } else {
                    f16 hv = (f16)v;
                    C16[row * ldc + col] = hv;
                    if (MODE == 4) {       // |mu_h|^2 from the ROUNDED value
                        float vr = (float)hv;
                        sq = fmaf(vr, vr, sq);
                    }
                }
            }
            if (MODE == 4) {   // |mu|^2 partial for this wave's 64 cols
                sq += __shfl_xor(sq, 1, 64); sq += __shfl_xor(sq, 2, 64);
                sq += __shfl_xor(sq, 4, 64); sq += __shfl_xor(sq, 8, 64);
                if (rA == 0) atomicAdd(&Mnorm[row], sq);
            }
        }
}

// ---------------------------------------------------------------------------
// proto_finish: one ROW PER LANE, zero shuffles in the proto loop.
// ---------------------------------------------------------------------------
__global__ __launch_bounds__(256)
void proto_finish(const f16* __restrict__ Xc, const float* __restrict__ Mnorm,
                  const float* __restrict__ Sr, const int* __restrict__ tcls,
                  const float* __restrict__ pnorm, const float* __restrict__ Wlast,
                  const float* __restrict__ opart,
                  float* __restrict__ out, float* __restrict__ kl_out)
{
    __shared__ float pnS[128], wlS[128], red[4];
    int t = threadIdx.x;
    if (t < 128) { pnS[t] = pnorm[t]; wlS[t] = Wlast[t]; }
    __syncthreads();

    int b = blockIdx.x * 256 + t;
    int cls = tcls[b];
    float Mn = Mnorm[b], Sb = Sr[b];
    const f16* xr = Xc + (size_t)b * 128 + cls * 16;
    f16x8 c0 = *(const f16x8*)xr;
    f16x8 c1 = *(const f16x8*)(xr + 8);

    float num = 0.f, den = 0.f, ov = 0.f;
#pragma unroll
    for (int p = 0; p < 16; ++p) {
        float c  = (p < 8) ? (float)c0[p] : (float)c1[p - 8];
        int  ip  = cls * 16 + p;
        float dd = fmaxf(Mn + pnS[ip] - 2.f * c, 0.f);
        float d  = sqrtf(dd);
        float sim = __logf((d + 1.f) / (d + EPS_SIM));
        float kl  = Sb + dd * (0.5f / 256.f);
        float klw = kl * sim;
        num += klw;
        den += (klw > 0.f) ? sim : 0.f;
        ov  += sim * wlS[ip];
    }
    out[b] = ov;

    float v = num / den;
#pragma unroll
    for (int off = 32; off; off >>= 1) v += __shfl_xor(v, off, 64);
    int lane = t & 63, w = t >> 6;
    if (lane == 0) red[w] = v;
    __syncthreads();
    if (t == 0)
        atomicAdd(kl_out, (red[0] + red[1] + red[2] + red[3]) * (1.f / (float)B_ROWS));
    if (blockIdx.x == 0 && t == 0) {
        float o = 0.f;
#pragma unroll
        for (int c8 = 0; c8 < 8; ++c8) o += opart[c8];
        out[OR_IDX] = o * (1.f / 8.f);
    }
}

// ---------------------------------------------------------------------------
extern "C" void kernel_launch(void* const* d_in, const int* in_sizes, int n_in,
                              void* d_out, int out_size, void* d_ws, size_t ws_size,
                              hipStream_t stream)
{
    const float* x      = (const float*)d_in[0];
    const int*   tcls   = (const int*)  d_in[1];
    const float* protos = (const float*)d_in[2];
    const float* W1     = (const float*)d_in[3];
    const float* b1     = (const float*)d_in[4];
    const float* W2     = (const float*)d_in[5];
    const float* b2     = (const float*)d_in[6];
    const float* Wd1    = (const float*)d_in[7];
    const float* bd1    = (const float*)d_in[8];
    const float* Wd2    = (const float*)d_in[9];
    const float* bd2    = (const float*)d_in[10];
    const float* Wlast  = (const float*)d_in[11];

    float* out     = (float*)d_out;
    float* decoded = out + B_ROWS;

    // h (f16, 16MB) lives in d_out's decoded region (33.5MB), overwritten by G4
    f16* h_h = (f16*)decoded;

    // workspace: mu_h 8MB | dh_h 8MB | S/munorm/pnorm/opart | weights | Xc 4MB
    f16* wsf  = (f16*)d_ws;
    f16* mu_h = wsf;                          // 4194304 f16
    f16* dh_h = wsf + 4194304;                // 4194304 f16

    float* S      = (float*)((char*)d_ws + 16777216);
    float* munorm = S + 16384;
    float* pnorm  = munorm + 16384;
    float* opart  = pnorm + 128;
    f16* w = (f16*)(opart + 8);
    f16 *W1h = w, *W2h = w + 262144, *Wd1h = w + 524288, *Wd2h = w + 589824;
    f16 *ph  = w + 720896;                    // protos f16 (128x256)
    f16* Xc = (f16*)((char*)d_ws + 20971520); // 20MB offset: 16384x128 f16 (4MB)

    // prep: ortho partials + weight conversions + pnorm + init (810 blocks)
    hipLaunchKernelGGL(prep_kernel, dim3(810), dim3(256), 0, stream,
                       W1, W2, Wd1, Wd2, protos,
                       W1h, W2h, Wd1h, Wd2h, ph,
                       pnorm, opart, S, munorm, out);

    // G1: h = relu(x @ W1^T + b1) -> f16  (A = f32 x, in-kernel convert)
    hipLaunchKernelGGL((gemm_mfma<0, 512, 1>), dim3(128, 4), dim3(256), 0, stream,
                       x, (f16*)nullptr, W1h, (f16*)nullptr, b1,
                       h_h, (float*)nullptr, (float*)nullptr, (float*)nullptr,
                       (f16*)nullptr, 512);
    // G2: conv = h @ W2^T + b2 -> mu f16 + |mu|^2 (y<2); S row-sums (y>=2)
    hipLaunchKernelGGL((gemm_mfma<4, 512, 0>), dim3(128, 4), dim3(256), 0, stream,
                       (float*)nullptr, h_h, W2h, (f16*)nullptr, b2,
                       mu_h, (float*)nullptr, S, munorm,
                       (f16*)nullptr, 256);
    // G3': y<2: dh = relu(mu @ Wd1^T + bd1); y==2: cross -> Xc (raw f16)
    hipLaunchKernelGGL((gemm_mfma<5, 256, 0>), dim3(128, 3), dim3(256), 0, stream,
                       (float*)nullptr, mu_h, Wd1h, ph, bd1,
                       dh_h, (float*)nullptr, (float*)nullptr, (float*)nullptr,
                       Xc, 256);
    // proto_finish: in-lane per-row d^2/sim/kl + out + kl mean + ortho fin
    hipLaunchKernelGGL(proto_finish, dim3(64), dim3(256), 0, stream,
                       Xc, munorm, S, tcls, pnorm, Wlast, opart,
                       out, out + KL_IDX);
    // G4: decoded = tanh(dh @ Wd2^T + bd2) -> f32 (overwrites h region)
    hipLaunchKernelGGL((gemm_mfma<3, 256, 0>), dim3(128, 4), dim3(256), 0, stream,
                       (float*)nullptr, dh_h, Wd2h, (f16*)nullptr, bd2,
                       (f16*)nullptr, decoded, (float*)nullptr, (float*)nullptr,
                       (f16*)nullptr, 512);
}

// Round 17
// 76.080 us; speedup vs baseline: 1.0941x; 1.0941x over previous
//
#include <hip/hip_runtime.h>
#include <math.h>

typedef _Float16 f16;
typedef f16   f16x4 __attribute__((ext_vector_type(4)));
typedef f16   f16x8 __attribute__((ext_vector_type(8)));
typedef float f32x4 __attribute__((ext_vector_type(4)));

#define B_ROWS 16384
#define PC 16
#define EPS_SIM 1e-4f
#define LOG_MIN_F (-18.420680743952367f)
#define KL_IDX  (B_ROWS + B_ROWS * 512)   // 8404992
#define OR_IDX  (KL_IDX + 1)

// direct global->LDS async copy, 16B per lane (lds dest = uniform base + lane*16)
#define GLD16(gp, lp) __builtin_amdgcn_global_load_lds( \
    (const __attribute__((address_space(1))) void*)(gp), \
    (__attribute__((address_space(3))) void*)(lp), 16, 0, 0)

// ---------------------------------------------------------------------------
// prep: ortho partials (blocks 0-7) + f32->f16 conversions + pnorm + init
// (round-14 form: x converted here; 9002 blocks)
// ---------------------------------------------------------------------------
__device__ __forceinline__ void conv4(const float* __restrict__ src,
                                      f16* __restrict__ dst, int i)
{
    float4 v = ((const float4*)src)[i];
    f16x4 o = { (f16)v.x, (f16)v.y, (f16)v.z, (f16)v.w };
    ((f16x4*)dst)[i] = o;
}

__global__ __launch_bounds__(256)
void prep_kernel(const float* __restrict__ x,   const float* __restrict__ W1,
                 const float* __restrict__ W2,  const float* __restrict__ Wd1,
                 const float* __restrict__ Wd2, const float* __restrict__ protos,
                 f16* __restrict__ x_h,  f16* __restrict__ W1h,
                 f16* __restrict__ W2h,  f16* __restrict__ Wd1h,
                 f16* __restrict__ Wd2h, f16* __restrict__ ph,
                 float* __restrict__ pnorm, float* __restrict__ opart,
                 float* __restrict__ S, float* __restrict__ Mn,
                 float* __restrict__ out)
{
    __shared__ float pk[PC][257];
    __shared__ float red[256];
    int blk = blockIdx.x, t = threadIdx.x;

    if (blk < 8) {                      // ortho: one class per block, parallel
        int c = blk;
        for (int i = t; i < PC * 256; i += 256)
            pk[i >> 8][i & 255] = protos[c * PC * 256 + i];
        __syncthreads();
        float mean = 0.f;
#pragma unroll
        for (int i = 0; i < PC; ++i) mean += pk[i][t];
        mean *= (1.f / (float)PC);
#pragma unroll
        for (int i = 0; i < PC; ++i) pk[i][t] -= mean;
        __syncthreads();
        int i = t >> 4, j = t & 15;
        float gg = 0.f;
#pragma unroll 8
        for (int l = 0; l < 256; ++l) gg = fmaf(pk[i][l], pk[j][l], gg);
        gg -= (i == j) ? 1.f : 0.f;
        red[t] = gg * gg;
        __syncthreads();
        for (int s = 128; s; s >>= 1) { if (t < s) red[t] += red[t + s]; __syncthreads(); }
        if (t == 0) opart[c] = sqrtf(red[0]);     // plain store, summed later
        return;
    }
    int b2 = blk - 8;
    if (b2 < 8192)         conv4(x,   x_h,  b2 * 256 + t);
    else if (b2 < 8448)    conv4(W1,  W1h,  (b2 - 8192) * 256 + t);
    else if (b2 < 8704)    conv4(W2,  W2h,  (b2 - 8448) * 256 + t);
    else if (b2 < 8768)    conv4(Wd1, Wd1h, (b2 - 8704) * 256 + t);
    else if (b2 < 8896)    conv4(Wd2, Wd2h, (b2 - 8768) * 256 + t);
    else if (b2 < 8928)    conv4(protos, ph, (b2 - 8896) * 256 + t);
    else if (b2 < 8930) {
        // pnorm from f16-ROUNDED protos (consistent with MFMA cross term)
        int tt = (b2 - 8928) * 256 + t;            // [0,512)
        int row = tt >> 2, q = tt & 3;
        const float* pr = protos + (size_t)row * 256 + q * 64;
        float s = 0.f;
#pragma unroll
        for (int j = 0; j < 16; ++j) {
            float4 v = *(const float4*)(pr + j * 4);
            float r0 = (float)(f16)v.x, r1 = (float)(f16)v.y;
            float r2 = (float)(f16)v.z, r3 = (float)(f16)v.w;
            s = fmaf(r0, r0, s); s = fmaf(r1, r1, s);
            s = fmaf(r2, r2, s); s = fmaf(r3, r3, s);
        }
        s += __shfl_xor(s, 1, 64);
        s += __shfl_xor(s, 2, 64);
        if (q == 0) pnorm[row] = s;
    } else {
        int i = (b2 - 8930) * 256 + t;             // [0,16384)
        S[i] = 0.f; Mn[i] = 0.f;
        if (i == 0) out[KL_IDX] = 0.f;
    }
}

// ---------------------------------------------------------------------------
// Pure-f16 MFMA GEMM, BM=128 x BN=128, BK=32, 4 waves (2x2, 64x64 each),
// DOUBLE-buffered 32KB LDS, ONE barrier per K-step:
//   barrier (drains stage(tk)) -> ds_read frags(buf tk) ->
//   issue stage(tk+1 -> buf^1) -> 16 MFMAs
// (buf^1's readers completed before the preceding barrier -> WAR-safe)
// MODE 0: relu -> f16 store
// MODE 3: tanh -> f32 store
// MODE 4: y<2 mu f16 store + |mu_h|^2 row-reduce; y>=2 logVar -> S row-reduce
// MODE 5: y<2 relu f16 store (dh); y==2 raw f16 cross -> Xc
// ---------------------------------------------------------------------------
template<int MODE, int KK>
__global__ __launch_bounds__(256, 2)
void gemm_mfma(const f16* __restrict__ A, const f16* __restrict__ B,
               const f16* __restrict__ P, const float* __restrict__ bias,
               f16* __restrict__ C16, float* __restrict__ Cf,
               float* __restrict__ Srow, float* __restrict__ Mnorm,
               f16* __restrict__ Xc, int ldc)
{
    __shared__ __align__(16) f16 LA[2][128][32];
    __shared__ __align__(16) f16 LB[2][128][32];

    const int t = threadIdx.x, lane = t & 63, wave = t >> 6;
    const int wm = wave >> 1, wn = wave & 1;
    const int bm = blockIdx.x * 128;
    const int y  = blockIdx.y;
    const bool proto = (MODE == 5) && (y == 2);
    const int bn  = y * 128;                      // output col base (non-proto)
    const int bnB = proto ? 0 : bn;               // B row base
    const f16* Bp = proto ? P : B;
    const int rA = lane & 15, g = lane >> 4;
    const int srow = lane >> 2, cp = lane & 3;    // staging: 16 rows x 4 chunks

    f32x4 acc[4][4];
    const f32x4 z4 = {0.f, 0.f, 0.f, 0.f};
#pragma unroll
    for (int i = 0; i < 4; ++i)
#pragma unroll
        for (int j = 0; j < 4; ++j) acc[i][j] = z4;

    auto stage = [&](int buf, int kt) {  // 4 GLD16 per thread
#pragma unroll
        for (int s = 0; s < 2; ++s) {
            int row = wave * 32 + s * 16 + srow;
            int lc  = (cp - (row >> 1)) & 3;      // inverse swizzle on SOURCE
            GLD16(A  + (size_t)(bm  + row) * KK + kt * 32 + lc * 8,
                  &LA[buf][wave * 32 + s * 16][0]);
            GLD16(Bp + (size_t)(bnB + row) * KK + kt * 32 + lc * 8,
                  &LB[buf][wave * 32 + s * 16][0]);
        }
    };

    constexpr int T = KK / 32;
    stage(0, 0);
    for (int tk = 0; tk < T; ++tk) {
        const int buf = tk & 1;
        __syncthreads();                 // drains vmcnt: tile tk resident

        f16x8 a[4], b[4];
#pragma unroll
        for (int i = 0; i < 4; ++i) {
            int m = wm * 64 + i * 16 + rA;
            int c = ((g + (m >> 1)) & 3) * 8;     // swizzled READ
            a[i] = *(const f16x8*)&LA[buf][m][c];
            int n = wn * 64 + i * 16 + rA;
            int cn = ((g + (n >> 1)) & 3) * 8;
            b[i] = *(const f16x8*)&LB[buf][n][cn];
        }

        if (tk + 1 < T) stage(buf ^ 1, tk + 1);   // WAR-safe: buf^1 readers
                                                  // drained at the barrier

#pragma unroll
        for (int i = 0; i < 4; ++i)
#pragma unroll
            for (int j = 0; j < 4; ++j)
                acc[i][j] = __builtin_amdgcn_mfma_f32_16x16x32_f16(a[i], b[j], acc[i][j], 0, 0, 0);
    }

    if (proto) {
        // raw cross-products -> Xc[16384][128] as f16 (no bias, no reduce)
#pragma unroll
        for (int i = 0; i < 4; ++i)
#pragma unroll
            for (int r = 0; r < 4; ++r) {
                size_t row = bm + wm * 64 + i * 16 + g * 4 + r;
#pragma unroll
                for (int j = 0; j < 4; ++j) {
                    int col = wn * 64 + j * 16 + rA;
                    Xc[row * 128 + col] = (f16)acc[i][j][r];
                }
            }
        return;
    }

    float bv[4];
#pragma unroll
    for (int j = 0; j < 4; ++j) bv[j] = bias[bn + wn * 64 + j * 16 + rA];

    if (MODE == 4 && y >= 2) {
        // logVar columns: S[row] += partial mean(0.5 e^lv - 0.5 lv - 0.5)
#pragma unroll
        for (int i = 0; i < 4; ++i)
#pragma unroll
            for (int r = 0; r < 4; ++r) {
                int row = bm + wm * 64 + i * 16 + g * 4 + r;
                float s = 0.f;
#pragma unroll
                for (int j = 0; j < 4; ++j) {
                    float lv = acc[i][j][r] + bv[j];
                    lv = fminf(fmaxf(lv, LOG_MIN_F), -LOG_MIN_F);
                    s += 0.5f * __expf(lv) - 0.5f * lv - 0.5f;
                }
                s += __shfl_xor(s, 1, 64); s += __shfl_xor(s, 2, 64);
                s += __shfl_xor(s, 4, 64); s += __shfl_xor(s, 8, 64);
                if (rA == 0) atomicAdd(&Srow[row], s * (1.f / 256.f));
            }
        return;
    }

#pragma unroll
    for (int i = 0; i < 4; ++i)
#pragma unroll
        for (int r = 0; r < 4; ++r) {
            size_t row = bm + wm * 64 + i * 16 + g * 4 + r;
            float sq = 0.f;
#pragma unroll
            for (int j = 0; j < 4; ++j) {
                int col = bn + wn * 64 + j * 16 + rA;
                float v = acc[i][j][r] + bv[j];
                if (MODE == 0 || MODE == 5) v = fmaxf(v, 0.f);
                if (MODE == 3) {
                    float e = __expf(2.f * v);
                    Cf[row * ldc + col] = 1.f - 2.f / (e + 1.f);
                } else {
                    f16 hv = (f16)v;
                    C16[row * ldc + col] = hv;
                    if (MODE == 4) {       // |mu_h|^2 from the ROUNDED value
                        float vr = (float)hv;
                        sq = fmaf(vr, vr, sq);
                    }
                }
            }
            if (MODE == 4) {   // |mu|^2 partial for this wave's 64 cols
                sq += __shfl_xor(sq, 1, 64); sq += __shfl_xor(sq, 2, 64);
                sq += __shfl_xor(sq, 4, 64); sq += __shfl_xor(sq, 8, 64);
                if (rA == 0) atomicAdd(&Mnorm[row], sq);
            }
        }
}

// ---------------------------------------------------------------------------
// proto_finish: one ROW PER LANE, zero shuffles in the proto loop.
// ---------------------------------------------------------------------------
__global__ __launch_bounds__(256)
void proto_finish(const f16* __restrict__ Xc, const float* __restrict__ Mnorm,
                  const float* __restrict__ Sr, const int* __restrict__ tcls,
                  const float* __restrict__ pnorm, const float* __restrict__ Wlast,
                  const float* __restrict__ opart,
                  float* __restrict__ out, float* __restrict__ kl_out)
{
    __shared__ float pnS[128], wlS[128], red[4];
    int t = threadIdx.x;
    if (t < 128) { pnS[t] = pnorm[t]; wlS[t] = Wlast[t]; }
    __syncthreads();

    int b = blockIdx.x * 256 + t;
    int cls = tcls[b];
    float Mn = Mnorm[b], Sb = Sr[b];
    const f16* xr = Xc + (size_t)b * 128 + cls * 16;
    f16x8 c0 = *(const f16x8*)xr;
    f16x8 c1 = *(const f16x8*)(xr + 8);

    float num = 0.f, den = 0.f, ov = 0.f;
#pragma unroll
    for (int p = 0; p < 16; ++p) {
        float c  = (p < 8) ? (float)c0[p] : (float)c1[p - 8];
        int  ip  = cls * 16 + p;
        float dd = fmaxf(Mn + pnS[ip] - 2.f * c, 0.f);
        float d  = sqrtf(dd);
        float sim = __logf((d + 1.f) / (d + EPS_SIM));
        float kl  = Sb + dd * (0.5f / 256.f);
        float klw = kl * sim;
        num += klw;
        den += (klw > 0.f) ? sim : 0.f;
        ov  += sim * wlS[ip];
    }
    out[b] = ov;

    float v = num / den;
#pragma unroll
    for (int off = 32; off; off >>= 1) v += __shfl_xor(v, off, 64);
    int lane = t & 63, w = t >> 6;
    if (lane == 0) red[w] = v;
    __syncthreads();
    if (t == 0)
        atomicAdd(kl_out, (red[0] + red[1] + red[2] + red[3]) * (1.f / (float)B_ROWS));
    if (blockIdx.x == 0 && t == 0) {
        float o = 0.f;
#pragma unroll
        for (int c8 = 0; c8 < 8; ++c8) o += opart[c8];
        out[OR_IDX] = o * (1.f / 8.f);
    }
}

// ---------------------------------------------------------------------------
extern "C" void kernel_launch(void* const* d_in, const int* in_sizes, int n_in,
                              void* d_out, int out_size, void* d_ws, size_t ws_size,
                              hipStream_t stream)
{
    const float* x      = (const float*)d_in[0];
    const int*   tcls   = (const int*)  d_in[1];
    const float* protos = (const float*)d_in[2];
    const float* W1     = (const float*)d_in[3];
    const float* b1     = (const float*)d_in[4];
    const float* W2     = (const float*)d_in[5];
    const float* b2     = (const float*)d_in[6];
    const float* Wd1    = (const float*)d_in[7];
    const float* bd1    = (const float*)d_in[8];
    const float* Wd2    = (const float*)d_in[9];
    const float* bd2    = (const float*)d_in[10];
    const float* Wlast  = (const float*)d_in[11];

    float* out     = (float*)d_out;
    float* decoded = out + B_ROWS;

    // h (f16, 16MB) lives in d_out's decoded region (33.5MB), overwritten by G4
    f16* h_h = (f16*)decoded;

    // workspace: x_h 16MB | mu_h 8MB | dh_h 8MB | S ... | weights ... | Xc 4MB
    f16* wsf  = (f16*)d_ws;
    f16* x_h  = wsf;                         // 8388608 f16
    f16* mu_h = wsf + 8388608;               // 4194304 f16
    f16* dh_h = wsf + 12582912;              // 4194304 f16

    float* S = (float*)((char*)d_ws + 33554432);
    f16* w = (f16*)(S + 32768);
    f16 *W1h = w, *W2h = w + 262144, *Wd1h = w + 524288, *Wd2h = w + 589824;
    f16 *ph  = w + 720896;                   // protos f16 (128x256)
    float* munorm = (float*)(w + 753664);    // 16384 f32
    float* pnorm  = munorm + 16384;          // 128 f32
    float* opart  = pnorm + 128;             // 8 f32
    f16* Xc = (f16*)((char*)d_ws + 37748736);// 36MB offset: 16384x128 f16 (4MB)

    // prep: ortho partials + conversions + pnorm + init
    hipLaunchKernelGGL(prep_kernel, dim3(9002), dim3(256), 0, stream,
                       x, W1, W2, Wd1, Wd2, protos,
                       x_h, W1h, W2h, Wd1h, Wd2h, ph,
                       pnorm, opart, S, munorm, out);

    // G1: h = relu(x @ W1^T + b1) -> f16
    hipLaunchKernelGGL((gemm_mfma<0, 512>), dim3(128, 4), dim3(256), 0, stream,
                       x_h, W1h, (f16*)nullptr, b1,
                       h_h, (float*)nullptr, (float*)nullptr, (float*)nullptr,
                       (f16*)nullptr, 512);
    // G2: conv = h @ W2^T + b2 -> mu f16 + |mu|^2 (y<2); S row-sums (y>=2)
    hipLaunchKernelGGL((gemm_mfma<4, 512>), dim3(128, 4), dim3(256), 0, stream,
                       h_h, W2h, (f16*)nullptr, b2,
                       mu_h, (float*)nullptr, S, munorm,
                       (f16*)nullptr, 256);
    // G3': y<2: dh = relu(mu @ Wd1^T + bd1); y==2: cross -> Xc (raw f16)
    hipLaunchKernelGGL((gemm_mfma<5, 256>), dim3(128, 3), dim3(256), 0, stream,
                       mu_h, Wd1h, ph, bd1,
                       dh_h, (float*)nullptr, (float*)nullptr, (float*)nullptr,
                       Xc, 256);
    // proto_finish: in-lane per-row d^2/sim/kl + out + kl mean + ortho fin
    hipLaunchKernelGGL(proto_finish, dim3(64), dim3(256), 0, stream,
                       Xc, munorm, S, tcls, pnorm, Wlast, opart,
                       out, out + KL_IDX);
    // G4: decoded = tanh(dh @ Wd2^T + bd2) -> f32 (overwrites h region)
    hipLaunchKernelGGL((gemm_mfma<3, 256>), dim3(128, 4), dim3(256), 0, stream,
                       dh_h, Wd2h, (f16*)nullptr, bd2,
                       (f16*)nullptr, decoded, (float*)nullptr, (float*)nullptr,
                       (f16*)nullptr, 512);
}

// Round 18
// 73.340 us; speedup vs baseline: 1.1350x; 1.0374x over previous
//
#include <hip/hip_runtime.h>
#include <math.h>

typedef _Float16 f16;
typedef f16   f16x4 __attribute__((ext_vector_type(4)));
typedef f16   f16x8 __attribute__((ext_vector_type(8)));
typedef float f32x4 __attribute__((ext_vector_type(4)));

#define B_ROWS 16384
#define PC 16
#define EPS_SIM 1e-4f
#define LOG_MIN_F (-18.420680743952367f)
#define KL_IDX  (B_ROWS + B_ROWS * 512)   // 8404992
#define OR_IDX  (KL_IDX + 1)

// direct global->LDS async copy, 16B per lane (lds dest = uniform base + lane*16)
#define GLD16(gp, lp) __builtin_amdgcn_global_load_lds( \
    (const __attribute__((address_space(1))) void*)(gp), \
    (__attribute__((address_space(3))) void*)(lp), 16, 0, 0)

// ---------------------------------------------------------------------------
// prep: ortho partials (blocks 0-7) + f32->f16 conversions + pnorm + init
// ---------------------------------------------------------------------------
__device__ __forceinline__ void conv4(const float* __restrict__ src,
                                      f16* __restrict__ dst, int i)
{
    float4 v = ((const float4*)src)[i];
    f16x4 o = { (f16)v.x, (f16)v.y, (f16)v.z, (f16)v.w };
    ((f16x4*)dst)[i] = o;
}

__global__ __launch_bounds__(256)
void prep_kernel(const float* __restrict__ x,   const float* __restrict__ W1,
                 const float* __restrict__ W2,  const float* __restrict__ Wd1,
                 const float* __restrict__ Wd2, const float* __restrict__ protos,
                 f16* __restrict__ x_h,  f16* __restrict__ W1h,
                 f16* __restrict__ W2h,  f16* __restrict__ Wd1h,
                 f16* __restrict__ Wd2h, f16* __restrict__ ph,
                 float* __restrict__ pnorm, float* __restrict__ opart,
                 float* __restrict__ S, float* __restrict__ Mn,
                 float* __restrict__ out)
{
    __shared__ float pk[PC][257];
    __shared__ float red[256];
    int blk = blockIdx.x, t = threadIdx.x;

    if (blk < 8) {                      // ortho: one class per block, parallel
        int c = blk;
        for (int i = t; i < PC * 256; i += 256)
            pk[i >> 8][i & 255] = protos[c * PC * 256 + i];
        __syncthreads();
        float mean = 0.f;
#pragma unroll
        for (int i = 0; i < PC; ++i) mean += pk[i][t];
        mean *= (1.f / (float)PC);
#pragma unroll
        for (int i = 0; i < PC; ++i) pk[i][t] -= mean;
        __syncthreads();
        int i = t >> 4, j = t & 15;
        float gg = 0.f;
#pragma unroll 8
        for (int l = 0; l < 256; ++l) gg = fmaf(pk[i][l], pk[j][l], gg);
        gg -= (i == j) ? 1.f : 0.f;
        red[t] = gg * gg;
        __syncthreads();
        for (int s = 128; s; s >>= 1) { if (t < s) red[t] += red[t + s]; __syncthreads(); }
        if (t == 0) opart[c] = sqrtf(red[0]);     // plain store, summed later
        return;
    }
    int b2 = blk - 8;
    if (b2 < 8192)         conv4(x,   x_h,  b2 * 256 + t);
    else if (b2 < 8448)    conv4(W1,  W1h,  (b2 - 8192) * 256 + t);
    else if (b2 < 8704)    conv4(W2,  W2h,  (b2 - 8448) * 256 + t);
    else if (b2 < 8768)    conv4(Wd1, Wd1h, (b2 - 8704) * 256 + t);
    else if (b2 < 8896)    conv4(Wd2, Wd2h, (b2 - 8768) * 256 + t);
    else if (b2 < 8928)    conv4(protos, ph, (b2 - 8896) * 256 + t);
    else if (b2 < 8930) {
        // pnorm from f16-ROUNDED protos (consistent with MFMA cross term)
        int tt = (b2 - 8928) * 256 + t;            // [0,512)
        int row = tt >> 2, q = tt & 3;
        const float* pr = protos + (size_t)row * 256 + q * 64;
        float s = 0.f;
#pragma unroll
        for (int j = 0; j < 16; ++j) {
            float4 v = *(const float4*)(pr + j * 4);
            float r0 = (float)(f16)v.x, r1 = (float)(f16)v.y;
            float r2 = (float)(f16)v.z, r3 = (float)(f16)v.w;
            s = fmaf(r0, r0, s); s = fmaf(r1, r1, s);
            s = fmaf(r2, r2, s); s = fmaf(r3, r3, s);
        }
        s += __shfl_xor(s, 1, 64);
        s += __shfl_xor(s, 2, 64);
        if (q == 0) pnorm[row] = s;
    } else {
        int i = (b2 - 8930) * 256 + t;             // [0,16384)
        S[i] = 0.f; Mn[i] = 0.f;
        if (i == 0) out[KL_IDX] = 0.f;
    }
}

// ---------------------------------------------------------------------------
// Pure-f16 MFMA GEMM, BM=128 x BN=128, BK=32, 4 waves (2x2, 64x64 each),
// DOUBLE-buffered LDS (aliased in LDSALL), ONE barrier per K-step:
//   barrier -> ds_read frags(buf tk) -> issue stage(tk+1 -> buf^1) -> MFMA
// MODE 0: relu -> f16 store
// MODE 3: tanh -> f32 store
// MODE 4: y<2 mu f16 store + |mu_h|^2 row-reduce; y>=2 logVar -> S row-reduce
// MODE 5: y<2 relu f16 store (dh); y==2 FUSED proto finish: acc -> LDS Xs
//         (stride 130, conflict-free) -> per-row in-lane d^2/sim/kl/out,
//         one kl atomic/block, ortho finalize in block x==0.
// ---------------------------------------------------------------------------
template<int MODE, int KK>
__global__ __launch_bounds__(256, 2)
void gemm_mfma(const f16* __restrict__ A, const f16* __restrict__ B,
               const f16* __restrict__ P, const float* __restrict__ bias,
               f16* __restrict__ C16, float* __restrict__ Cf,
               float* __restrict__ Srow, float* __restrict__ Mnorm,
               const int* __restrict__ tcls, const float* __restrict__ pnorm,
               const float* __restrict__ Wlast, const float* __restrict__ opart,
               float* __restrict__ out, float* __restrict__ kl_out, int ldc)
{
    // 33,280 B: stage buffers (32KB) and proto Xs[128][130] alias this region
    __shared__ __align__(16) f16 LDSALL[16640];
    f16 (*LA)[128][32] = reinterpret_cast<f16(*)[128][32]>(LDSALL);
    f16 (*LB)[128][32] = reinterpret_cast<f16(*)[128][32]>(LDSALL + 8192);
    __shared__ float redk[2];

    const int t = threadIdx.x, lane = t & 63, wave = t >> 6;
    const int wm = wave >> 1, wn = wave & 1;
    const int bm = blockIdx.x * 128;
    const int y  = blockIdx.y;
    const bool proto = (MODE == 5) && (y == 2);
    const int bn  = y * 128;                      // output col base (non-proto)
    const int bnB = proto ? 0 : bn;               // B row base
    const f16* Bp = proto ? P : B;
    const int rA = lane & 15, g = lane >> 4;
    const int srow = lane >> 2, cp = lane & 3;    // staging: 16 rows x 4 chunks

    f32x4 acc[4][4];
    const f32x4 z4 = {0.f, 0.f, 0.f, 0.f};
#pragma unroll
    for (int i = 0; i < 4; ++i)
#pragma unroll
        for (int j = 0; j < 4; ++j) acc[i][j] = z4;

    auto stage = [&](int buf, int kt) {  // 4 GLD16 per thread
#pragma unroll
        for (int s = 0; s < 2; ++s) {
            int row = wave * 32 + s * 16 + srow;
            int lc  = (cp - (row >> 1)) & 3;      // inverse swizzle on SOURCE
            GLD16(A  + (size_t)(bm  + row) * KK + kt * 32 + lc * 8,
                  &LA[buf][wave * 32 + s * 16][0]);
            GLD16(Bp + (size_t)(bnB + row) * KK + kt * 32 + lc * 8,
                  &LB[buf][wave * 32 + s * 16][0]);
        }
    };

    constexpr int T = KK / 32;
    stage(0, 0);
    for (int tk = 0; tk < T; ++tk) {
        const int buf = tk & 1;
        __syncthreads();                 // drains vmcnt: tile tk resident

        f16x8 a[4], b[4];
#pragma unroll
        for (int i = 0; i < 4; ++i) {
            int m = wm * 64 + i * 16 + rA;
            int c = ((g + (m >> 1)) & 3) * 8;     // swizzled READ
            a[i] = *(const f16x8*)&LA[buf][m][c];
            int n = wn * 64 + i * 16 + rA;
            int cn = ((g + (n >> 1)) & 3) * 8;
            b[i] = *(const f16x8*)&LB[buf][n][cn];
        }

        if (tk + 1 < T) stage(buf ^ 1, tk + 1);   // WAR-safe: buf^1 readers
                                                  // drained at the barrier

#pragma unroll
        for (int i = 0; i < 4; ++i)
#pragma unroll
            for (int j = 0; j < 4; ++j)
                acc[i][j] = __builtin_amdgcn_mfma_f32_16x16x32_f16(a[i], b[j], acc[i][j], 0, 0, 0);
    }

    if (proto) {
        // acc -> LDS Xs[128][130] f16 (stride 130 -> word-stride 65, odd:
        // per-row reads hit distinct banks), then per-row in-lane finish.
        f16* Xs = LDSALL;
        __syncthreads();                 // stage-buffer readers all done
#pragma unroll
        for (int i = 0; i < 4; ++i)
#pragma unroll
            for (int r = 0; r < 4; ++r) {
                int rowl = wm * 64 + i * 16 + g * 4 + r;
#pragma unroll
                for (int j = 0; j < 4; ++j) {
                    int col = wn * 64 + j * 16 + rA;
                    Xs[rowl * 130 + col] = (f16)acc[i][j][r];
                }
            }
        __syncthreads();

        float v = 0.f;
        if (t < 128) {
            int row = bm + t;
            int cls = tcls[row];
            float Mn = Mnorm[row], Sb = Srow[row];
            const f16* xr = Xs + t * 130 + cls * 16;
            float num = 0.f, den = 0.f, ov = 0.f;
#pragma unroll
            for (int p = 0; p < 16; ++p) {
                float c  = (float)xr[p];
                int  ip  = cls * 16 + p;
                float dd = fmaxf(Mn + pnorm[ip] - 2.f * c, 0.f);
                float d  = sqrtf(dd);
                float sim = __logf((d + 1.f) / (d + EPS_SIM));
                float kl  = Sb + dd * (0.5f / 256.f);
                float klw = kl * sim;
                num += klw;
                den += (klw > 0.f) ? sim : 0.f;
                ov  += sim * Wlast[ip];
            }
            out[row] = ov;
            v = num / den;
        }
#pragma unroll
        for (int off = 32; off; off >>= 1) v += __shfl_xor(v, off, 64);
        if (t < 128 && (t & 63) == 0) redk[t >> 6] = v;
        __syncthreads();
        if (t == 0)
            atomicAdd(kl_out, (redk[0] + redk[1]) * (1.f / (float)B_ROWS));
        if (blockIdx.x == 0 && t == 0) {
            float o = 0.f;
#pragma unroll
            for (int c8 = 0; c8 < 8; ++c8) o += opart[c8];
            out[OR_IDX] = o * (1.f / 8.f);
        }
        return;
    }

    float bv[4];
#pragma unroll
    for (int j = 0; j < 4; ++j) bv[j] = bias[bn + wn * 64 + j * 16 + rA];

    if (MODE == 4 && y >= 2) {
        // logVar columns: S[row] += partial mean(0.5 e^lv - 0.5 lv - 0.5)
#pragma unroll
        for (int i = 0; i < 4; ++i)
#pragma unroll
            for (int r = 0; r < 4; ++r) {
                int row = bm + wm * 64 + i * 16 + g * 4 + r;
                float s = 0.f;
#pragma unroll
                for (int j = 0; j < 4; ++j) {
                    float lv = acc[i][j][r] + bv[j];
                    lv = fminf(fmaxf(lv, LOG_MIN_F), -LOG_MIN_F);
                    s += 0.5f * __expf(lv) - 0.5f * lv - 0.5f;
                }
                s += __shfl_xor(s, 1, 64); s += __shfl_xor(s, 2, 64);
                s += __shfl_xor(s, 4, 64); s += __shfl_xor(s, 8, 64);
                if (rA == 0) atomicAdd(&Srow[row], s * (1.f / 256.f));
            }
        return;
    }

#pragma unroll
    for (int i = 0; i < 4; ++i)
#pragma unroll
        for (int r = 0; r < 4; ++r) {
            size_t row = bm + wm * 64 + i * 16 + g * 4 + r;
            float sq = 0.f;
#pragma unroll
            for (int j = 0; j < 4; ++j) {
                int col = bn + wn * 64 + j * 16 + rA;
                float v = acc[i][j][r] + bv[j];
                if (MODE == 0 || MODE == 5) v = fmaxf(v, 0.f);
                if (MODE == 3) {
                    float e = __expf(2.f * v);
                    Cf[row * ldc + col] = 1.f - 2.f / (e + 1.f);
                } else {
                    f16 hv = (f16)v;
                    C16[row * ldc + col] = hv;
                    if (MODE == 4) {       // |mu_h|^2 from the ROUNDED value
                        float vr = (float)hv;
                        sq = fmaf(vr, vr, sq);
                    }
                }
            }
            if (MODE == 4) {   // |mu|^2 partial for this wave's 64 cols
                sq += __shfl_xor(sq, 1, 64); sq += __shfl_xor(sq, 2, 64);
                sq += __shfl_xor(sq, 4, 64); sq += __shfl_xor(sq, 8, 64);
                if (rA == 0) atomicAdd(&Mnorm[row], sq);
            }
        }
}

// ---------------------------------------------------------------------------
extern "C" void kernel_launch(void* const* d_in, const int* in_sizes, int n_in,
                              void* d_out, int out_size, void* d_ws, size_t ws_size,
                              hipStream_t stream)
{
    const float* x      = (const float*)d_in[0];
    const int*   tcls   = (const int*)  d_in[1];
    const float* protos = (const float*)d_in[2];
    const float* W1     = (const float*)d_in[3];
    const float* b1     = (const float*)d_in[4];
    const float* W2     = (const float*)d_in[5];
    const float* b2     = (const float*)d_in[6];
    const float* Wd1    = (const float*)d_in[7];
    const float* bd1    = (const float*)d_in[8];
    const float* Wd2    = (const float*)d_in[9];
    const float* bd2    = (const float*)d_in[10];
    const float* Wlast  = (const float*)d_in[11];

    float* out     = (float*)d_out;
    float* decoded = out + B_ROWS;

    // h (f16, 16MB) lives in d_out's decoded region (33.5MB), overwritten by G4
    f16* h_h = (f16*)decoded;

    // workspace: x_h 16MB | mu_h 8MB | dh_h 8MB | S ... | weights ...
    f16* wsf  = (f16*)d_ws;
    f16* x_h  = wsf;                         // 8388608 f16
    f16* mu_h = wsf + 8388608;               // 4194304 f16
    f16* dh_h = wsf + 12582912;              // 4194304 f16

    float* S = (float*)((char*)d_ws + 33554432);
    f16* w = (f16*)(S + 32768);
    f16 *W1h = w, *W2h = w + 262144, *Wd1h = w + 524288, *Wd2h = w + 589824;
    f16 *ph  = w + 720896;                   // protos f16 (128x256)
    float* munorm = (float*)(w + 753664);    // 16384 f32
    float* pnorm  = munorm + 16384;          // 128 f32
    float* opart  = pnorm + 128;             // 8 f32

    // prep: ortho partials + conversions + pnorm + init
    hipLaunchKernelGGL(prep_kernel, dim3(9002), dim3(256), 0, stream,
                       x, W1, W2, Wd1, Wd2, protos,
                       x_h, W1h, W2h, Wd1h, Wd2h, ph,
                       pnorm, opart, S, munorm, out);

    // G1: h = relu(x @ W1^T + b1) -> f16
    hipLaunchKernelGGL((gemm_mfma<0, 512>), dim3(128, 4), dim3(256), 0, stream,
                       x_h, W1h, (f16*)nullptr, b1,
                       h_h, (float*)nullptr, (float*)nullptr, (float*)nullptr,
                       (int*)nullptr, (float*)nullptr, (float*)nullptr,
                       (float*)nullptr, (float*)nullptr, (float*)nullptr, 512);
    // G2: conv = h @ W2^T + b2 -> mu f16 + |mu|^2 (y<2); S row-sums (y>=2)
    hipLaunchKernelGGL((gemm_mfma<4, 512>), dim3(128, 4), dim3(256), 0, stream,
                       h_h, W2h, (f16*)nullptr, b2,
                       mu_h, (float*)nullptr, S, munorm,
                       (int*)nullptr, (float*)nullptr, (float*)nullptr,
                       (float*)nullptr, (float*)nullptr, (float*)nullptr, 256);
    // G3': y<2: dh = relu(mu @ Wd1^T + bd1); y==2: proto cross + FUSED finish
    hipLaunchKernelGGL((gemm_mfma<5, 256>), dim3(128, 3), dim3(256), 0, stream,
                       mu_h, Wd1h, ph, bd1,
                       dh_h, (float*)nullptr, S, munorm,
                       tcls, pnorm, Wlast, opart,
                       out, out + KL_IDX, 256);
    // G4: decoded = tanh(dh @ Wd2^T + bd2) -> f32 (overwrites h region)
    hipLaunchKernelGGL((gemm_mfma<3, 256>), dim3(128, 4), dim3(256), 0, stream,
                       dh_h, Wd2h, (f16*)nullptr, bd2,
                       (f16*)nullptr, decoded, (float*)nullptr, (float*)nullptr,
                       (int*)nullptr, (float*)nullptr, (float*)nullptr,
                       (float*)nullptr, (float*)nullptr, (float*)nullptr, 512);
}

// Round 19
// 68.059 us; speedup vs baseline: 1.2230x; 1.0776x over previous
//
#include <hip/hip_runtime.h>
#include <math.h>

typedef _Float16 f16;
typedef f16   f16x4 __attribute__((ext_vector_type(4)));
typedef f16   f16x8 __attribute__((ext_vector_type(8)));
typedef float f32x4 __attribute__((ext_vector_type(4)));

#define B_ROWS 16384
#define PC 16
#define EPS_SIM 1e-4f
#define LOG_MIN_F (-18.420680743952367f)
#define KL_IDX  (B_ROWS + B_ROWS * 512)   // 8404992
#define OR_IDX  (KL_IDX + 1)

// direct global->LDS async copy, 16B per lane (lds dest = uniform base + lane*16)
#define GLD16(gp, lp) __builtin_amdgcn_global_load_lds( \
    (const __attribute__((address_space(1))) void*)(gp), \
    (__attribute__((address_space(3))) void*)(lp), 16, 0, 0)

// ---------------------------------------------------------------------------
// prep: ortho partials (blocks 0-7) + f32->f16 conversions + pnorm + init
// ---------------------------------------------------------------------------
__device__ __forceinline__ void conv4(const float* __restrict__ src,
                                      f16* __restrict__ dst, int i)
{
    float4 v = ((const float4*)src)[i];
    f16x4 o = { (f16)v.x, (f16)v.y, (f16)v.z, (f16)v.w };
    ((f16x4*)dst)[i] = o;
}

__global__ __launch_bounds__(256)
void prep_kernel(const float* __restrict__ x,   const float* __restrict__ W1,
                 const float* __restrict__ W2,  const float* __restrict__ Wd1,
                 const float* __restrict__ Wd2, const float* __restrict__ protos,
                 f16* __restrict__ x_h,  f16* __restrict__ W1h,
                 f16* __restrict__ W2h,  f16* __restrict__ Wd1h,
                 f16* __restrict__ Wd2h, f16* __restrict__ ph,
                 float* __restrict__ pnorm, float* __restrict__ opart,
                 float* __restrict__ S, float* __restrict__ Mn,
                 float* __restrict__ out)
{
    __shared__ float pk[PC][257];
    __shared__ float red[256];
    int blk = blockIdx.x, t = threadIdx.x;

    if (blk < 8) {                      // ortho: one class per block, parallel
        int c = blk;
        for (int i = t; i < PC * 256; i += 256)
            pk[i >> 8][i & 255] = protos[c * PC * 256 + i];
        __syncthreads();
        float mean = 0.f;
#pragma unroll
        for (int i = 0; i < PC; ++i) mean += pk[i][t];
        mean *= (1.f / (float)PC);
#pragma unroll
        for (int i = 0; i < PC; ++i) pk[i][t] -= mean;
        __syncthreads();
        int i = t >> 4, j = t & 15;
        float gg = 0.f;
#pragma unroll 8
        for (int l = 0; l < 256; ++l) gg = fmaf(pk[i][l], pk[j][l], gg);
        gg -= (i == j) ? 1.f : 0.f;
        red[t] = gg * gg;
        __syncthreads();
        for (int s = 128; s; s >>= 1) { if (t < s) red[t] += red[t + s]; __syncthreads(); }
        if (t == 0) opart[c] = sqrtf(red[0]);     // plain store, summed later
        return;
    }
    int b2 = blk - 8;
    if (b2 < 8192)         conv4(x,   x_h,  b2 * 256 + t);
    else if (b2 < 8448)    conv4(W1,  W1h,  (b2 - 8192) * 256 + t);
    else if (b2 < 8704)    conv4(W2,  W2h,  (b2 - 8448) * 256 + t);
    else if (b2 < 8768)    conv4(Wd1, Wd1h, (b2 - 8704) * 256 + t);
    else if (b2 < 8896)    conv4(Wd2, Wd2h, (b2 - 8768) * 256 + t);
    else if (b2 < 8928)    conv4(protos, ph, (b2 - 8896) * 256 + t);
    else if (b2 < 8930) {
        // pnorm from f16-ROUNDED protos (consistent with MFMA cross term)
        int tt = (b2 - 8928) * 256 + t;            // [0,512)
        int row = tt >> 2, q = tt & 3;
        const float* pr = protos + (size_t)row * 256 + q * 64;
        float s = 0.f;
#pragma unroll
        for (int j = 0; j < 16; ++j) {
            float4 v = *(const float4*)(pr + j * 4);
            float r0 = (float)(f16)v.x, r1 = (float)(f16)v.y;
            float r2 = (float)(f16)v.z, r3 = (float)(f16)v.w;
            s = fmaf(r0, r0, s); s = fmaf(r1, r1, s);
            s = fmaf(r2, r2, s); s = fmaf(r3, r3, s);
        }
        s += __shfl_xor(s, 1, 64);
        s += __shfl_xor(s, 2, 64);
        if (q == 0) pnorm[row] = s;
    } else {
        int i = (b2 - 8930) * 256 + t;             // [0,16384)
        S[i] = 0.f; Mn[i] = 0.f;
        if (i == 0) out[KL_IDX] = 0.f;
    }
}

// ---------------------------------------------------------------------------
// Pure-f16 MFMA GEMM, BM=128 x BN=128, BK=64, 4 waves (2x2, 64x64 each),
// DOUBLE-buffered 64KB LDS, ONE barrier per K-step (T = KK/64):
//   barrier -> ds_read frags(buf tk) -> issue stage(tk+1 -> buf^1) -> 32 MFMA
// 8-chunk XOR swizzle: source chunk (cp-row)&7, read chunk (h*4+g+m)&7.
// All grids are 2 blocks/CU; 64KB dbuf keeps exactly 2 -> no occupancy loss,
// half the barrier convoys vs BK=32.
// MODE 0: relu -> f16 store
// MODE 3: tanh -> f32 store
// MODE 4: y<2 mu f16 store + |mu_h|^2 row-reduce; y>=2 logVar -> S row-reduce
// MODE 5: y<2 relu f16 store (dh); y==2 FUSED proto finish (LDS Xs transpose,
//         per-row in-lane d^2/sim/kl/out, 1 kl atomic/block, ortho fin x==0)
// ---------------------------------------------------------------------------
template<int MODE, int KK>
__global__ __launch_bounds__(256, 2)
void gemm_mfma(const f16* __restrict__ A, const f16* __restrict__ B,
               const f16* __restrict__ P, const float* __restrict__ bias,
               f16* __restrict__ C16, float* __restrict__ Cf,
               float* __restrict__ Srow, float* __restrict__ Mnorm,
               const int* __restrict__ tcls, const float* __restrict__ pnorm,
               const float* __restrict__ Wlast, const float* __restrict__ opart,
               float* __restrict__ out, float* __restrict__ kl_out, int ldc)
{
    // 64KB: 2 x (A[128][64] + B[128][64]) f16; proto Xs[128][130] aliases it
    __shared__ __align__(16) f16 LDSALL[32768];
    f16 (*LA)[128][64] = reinterpret_cast<f16(*)[128][64]>(LDSALL);
    f16 (*LB)[128][64] = reinterpret_cast<f16(*)[128][64]>(LDSALL + 16384);
    __shared__ float redk[2];

    const int t = threadIdx.x, lane = t & 63, wave = t >> 6;
    const int wm = wave >> 1, wn = wave & 1;
    const int bm = blockIdx.x * 128;
    const int y  = blockIdx.y;
    const bool proto = (MODE == 5) && (y == 2);
    const int bn  = y * 128;                      // output col base (non-proto)
    const int bnB = proto ? 0 : bn;               // B row base
    const f16* Bp = proto ? P : B;
    const int rA = lane & 15, g = lane >> 4;
    const int wrow8 = lane >> 3, cp8 = lane & 7;  // staging: 8 rows x 8 chunks

    f32x4 acc[4][4];
    const f32x4 z4 = {0.f, 0.f, 0.f, 0.f};
#pragma unroll
    for (int i = 0; i < 4; ++i)
#pragma unroll
        for (int j = 0; j < 4; ++j) acc[i][j] = z4;

    auto stage = [&](int buf, int kt) {  // 8 GLD16 per thread
#pragma unroll
        for (int s = 0; s < 4; ++s) {
            int row = wave * 32 + s * 8 + wrow8;
            int lc  = (cp8 - row) & 7;            // inverse swizzle on SOURCE
            GLD16(A  + (size_t)(bm  + row) * KK + kt * 64 + lc * 8,
                  &LA[buf][wave * 32 + s * 8][0]);
            GLD16(Bp + (size_t)(bnB + row) * KK + kt * 64 + lc * 8,
                  &LB[buf][wave * 32 + s * 8][0]);
        }
    };

    constexpr int T = KK / 64;
    stage(0, 0);
    for (int tk = 0; tk < T; ++tk) {
        const int buf = tk & 1;
        __syncthreads();                 // drains vmcnt: tile tk resident

        f16x8 a[2][4], b[2][4];          // [k-half][frag]
#pragma unroll
        for (int h = 0; h < 2; ++h)
#pragma unroll
            for (int i = 0; i < 4; ++i) {
                int m = wm * 64 + i * 16 + rA;
                a[h][i] = *(const f16x8*)&LA[buf][m][((h * 4 + g + m) & 7) * 8];
                int n = wn * 64 + i * 16 + rA;
                b[h][i] = *(const f16x8*)&LB[buf][n][((h * 4 + g + n) & 7) * 8];
            }

        if (tk + 1 < T) stage(buf ^ 1, tk + 1);   // WAR-safe: buf^1 readers
                                                  // drained at the barrier

#pragma unroll
        for (int h = 0; h < 2; ++h)
#pragma unroll
            for (int i = 0; i < 4; ++i)
#pragma unroll
                for (int j = 0; j < 4; ++j)
                    acc[i][j] = __builtin_amdgcn_mfma_f32_16x16x32_f16(a[h][i], b[h][j], acc[i][j], 0, 0, 0);
    }

    if (proto) {
        // acc -> LDS Xs[128][130] f16 (word-stride 65: odd, conflict-light),
        // then per-row in-lane finish (zero shuffles in the proto loop).
        f16* Xs = LDSALL;
        __syncthreads();                 // stage-buffer readers all done
#pragma unroll
        for (int i = 0; i < 4; ++i)
#pragma unroll
            for (int r = 0; r < 4; ++r) {
                int rowl = wm * 64 + i * 16 + g * 4 + r;
#pragma unroll
                for (int j = 0; j < 4; ++j) {
                    int col = wn * 64 + j * 16 + rA;
                    Xs[rowl * 130 + col] = (f16)acc[i][j][r];
                }
            }
        __syncthreads();

        float v = 0.f;
        if (t < 128) {
            int row = bm + t;
            int cls = tcls[row];
            float Mn = Mnorm[row], Sb = Srow[row];
            const f16* xr = Xs + t * 130 + cls * 16;
            float num = 0.f, den = 0.f, ov = 0.f;
#pragma unroll
            for (int p = 0; p < 16; ++p) {
                float c  = (float)xr[p];
                int  ip  = cls * 16 + p;
                float dd = fmaxf(Mn + pnorm[ip] - 2.f * c, 0.f);
                float d  = sqrtf(dd);
                float sim = __logf((d + 1.f) / (d + EPS_SIM));
                float kl  = Sb + dd * (0.5f / 256.f);
                float klw = kl * sim;
                num += klw;
                den += (klw > 0.f) ? sim : 0.f;
                ov  += sim * Wlast[ip];
            }
            out[row] = ov;
            v = num / den;
        }
#pragma unroll
        for (int off = 32; off; off >>= 1) v += __shfl_xor(v, off, 64);
        if (t < 128 && (t & 63) == 0) redk[t >> 6] = v;
        __syncthreads();
        if (t == 0)
            atomicAdd(kl_out, (redk[0] + redk[1]) * (1.f / (float)B_ROWS));
        if (blockIdx.x == 0 && t == 0) {
            float o = 0.f;
#pragma unroll
            for (int c8 = 0; c8 < 8; ++c8) o += opart[c8];
            out[OR_IDX] = o * (1.f / 8.f);
        }
        return;
    }

    float bv[4];
#pragma unroll
    for (int j = 0; j < 4; ++j) bv[j] = bias[bn + wn * 64 + j * 16 + rA];

    if (MODE == 4 && y >= 2) {
        // logVar columns: S[row] += partial mean(0.5 e^lv - 0.5 lv - 0.5)
#pragma unroll
        for (int i = 0; i < 4; ++i)
#pragma unroll
            for (int r = 0; r < 4; ++r) {
                int row = bm + wm * 64 + i * 16 + g * 4 + r;
                float s = 0.f;
#pragma unroll
                for (int j = 0; j < 4; ++j) {
                    float lv = acc[i][j][r] + bv[j];
                    lv = fminf(fmaxf(lv, LOG_MIN_F), -LOG_MIN_F);
                    s += 0.5f * __expf(lv) - 0.5f * lv - 0.5f;
                }
                s += __shfl_xor(s, 1, 64); s += __shfl_xor(s, 2, 64);
                s += __shfl_xor(s, 4, 64); s += __shfl_xor(s, 8, 64);
                if (rA == 0) atomicAdd(&Srow[row], s * (1.f / 256.f));
            }
        return;
    }

#pragma unroll
    for (int i = 0; i < 4; ++i)
#pragma unroll
        for (int r = 0; r < 4; ++r) {
            size_t row = bm + wm * 64 + i * 16 + g * 4 + r;
            float sq = 0.f;
#pragma unroll
            for (int j = 0; j < 4; ++j) {
                int col = bn + wn * 64 + j * 16 + rA;
                float v = acc[i][j][r] + bv[j];
                if (MODE == 0 || MODE == 5) v = fmaxf(v, 0.f);
                if (MODE == 3) {
                    float e = __expf(2.f * v);
                    Cf[row * ldc + col] = 1.f - 2.f / (e + 1.f);
                } else {
                    f16 hv = (f16)v;
                    C16[row * ldc + col] = hv;
                    if (MODE == 4) {       // |mu_h|^2 from the ROUNDED value
                        float vr = (float)hv;
                        sq = fmaf(vr, vr, sq);
                    }
                }
            }
            if (MODE == 4) {   // |mu|^2 partial for this wave's 64 cols
                sq += __shfl_xor(sq, 1, 64); sq += __shfl_xor(sq, 2, 64);
                sq += __shfl_xor(sq, 4, 64); sq += __shfl_xor(sq, 8, 64);
                if (rA == 0) atomicAdd(&Mnorm[row], sq);
            }
        }
}

// ---------------------------------------------------------------------------
extern "C" void kernel_launch(void* const* d_in, const int* in_sizes, int n_in,
                              void* d_out, int out_size, void* d_ws, size_t ws_size,
                              hipStream_t stream)
{
    const float* x      = (const float*)d_in[0];
    const int*   tcls   = (const int*)  d_in[1];
    const float* protos = (const float*)d_in[2];
    const float* W1     = (const float*)d_in[3];
    const float* b1     = (const float*)d_in[4];
    const float* W2     = (const float*)d_in[5];
    const float* b2     = (const float*)d_in[6];
    const float* Wd1    = (const float*)d_in[7];
    const float* bd1    = (const float*)d_in[8];
    const float* Wd2    = (const float*)d_in[9];
    const float* bd2    = (const float*)d_in[10];
    const float* Wlast  = (const float*)d_in[11];

    float* out     = (float*)d_out;
    float* decoded = out + B_ROWS;

    // h (f16, 16MB) lives in d_out's decoded region (33.5MB), overwritten by G4
    f16* h_h = (f16*)decoded;

    // workspace: x_h 16MB | mu_h 8MB | dh_h 8MB | S ... | weights ...
    f16* wsf  = (f16*)d_ws;
    f16* x_h  = wsf;                         // 8388608 f16
    f16* mu_h = wsf + 8388608;               // 4194304 f16
    f16* dh_h = wsf + 12582912;              // 4194304 f16

    float* S = (float*)((char*)d_ws + 33554432);
    f16* w = (f16*)(S + 32768);
    f16 *W1h = w, *W2h = w + 262144, *Wd1h = w + 524288, *Wd2h = w + 589824;
    f16 *ph  = w + 720896;                   // protos f16 (128x256)
    float* munorm = (float*)(w + 753664);    // 16384 f32
    float* pnorm  = munorm + 16384;          // 128 f32
    float* opart  = pnorm + 128;             // 8 f32

    // prep: ortho partials + conversions + pnorm + init
    hipLaunchKernelGGL(prep_kernel, dim3(9002), dim3(256), 0, stream,
                       x, W1, W2, Wd1, Wd2, protos,
                       x_h, W1h, W2h, Wd1h, Wd2h, ph,
                       pnorm, opart, S, munorm, out);

    // G1: h = relu(x @ W1^T + b1) -> f16
    hipLaunchKernelGGL((gemm_mfma<0, 512>), dim3(128, 4), dim3(256), 0, stream,
                       x_h, W1h, (f16*)nullptr, b1,
                       h_h, (float*)nullptr, (float*)nullptr, (float*)nullptr,
                       (int*)nullptr, (float*)nullptr, (float*)nullptr,
                       (float*)nullptr, (float*)nullptr, (float*)nullptr, 512);
    // G2: conv = h @ W2^T + b2 -> mu f16 + |mu|^2 (y<2); S row-sums (y>=2)
    hipLaunchKernelGGL((gemm_mfma<4, 512>), dim3(128, 4), dim3(256), 0, stream,
                       h_h, W2h, (f16*)nullptr, b2,
                       mu_h, (float*)nullptr, S, munorm,
                       (int*)nullptr, (float*)nullptr, (float*)nullptr,
                       (float*)nullptr, (float*)nullptr, (float*)nullptr, 256);
    // G3': y<2: dh = relu(mu @ Wd1^T + bd1); y==2: proto cross + FUSED finish
    hipLaunchKernelGGL((gemm_mfma<5, 256>), dim3(128, 3), dim3(256), 0, stream,
                       mu_h, Wd1h, ph, bd1,
                       dh_h, (float*)nullptr, S, munorm,
                       tcls, pnorm, Wlast, opart,
                       out, out + KL_IDX, 256);
    // G4: decoded = tanh(dh @ Wd2^T + bd2) -> f32 (overwrites h region)
    hipLaunchKernelGGL((gemm_mfma<3, 256>), dim3(128, 4), dim3(256), 0, stream,
                       dh_h, Wd2h, (f16*)nullptr, bd2,
                       (f16*)nullptr, decoded, (float*)nullptr, (float*)nullptr,
                       (int*)nullptr, (float*)nullptr, (float*)nullptr,
                       (float*)nullptr, (float*)nullptr, (float*)nullptr, 512);
}